// Round 4
// baseline (630.916 us; speedup 1.0000x reference)
//
#include <hip/hip_runtime.h>
#include <stdint.h>

#define EDGES 200000
#define INF   128
#define HID   32
#define NHEAD 4
#define OUTF  128
#define MAXK  16
#define NEDGE 8      // edges per wave in attn

// padded combined-projection feature count: q(128) g(128) kv(256) b(4) pad(12)
#define NPAD  528
#define NTILES 33

typedef unsigned short u16;
typedef __attribute__((ext_vector_type(8))) short bf16x8;   // 8 bf16 = 4 VGPRs
typedef __attribute__((ext_vector_type(4))) float f32x4;

__device__ __forceinline__ u16 f2bf(float f) {   // RNE f32->bf16
  union { float f; uint32_t u; } v; v.f = f;
  uint32_t u = v.u;
  return (u16)((u + 0x7FFFu + ((u >> 16) & 1u)) >> 16);
}
__device__ __forceinline__ float bflo(uint32_t p) {
  union { uint32_t u; float f; } v; v.u = p << 16;
  return v.f;
}
__device__ __forceinline__ float bfhi(uint32_t p) {
  union { uint32_t u; float f; } v; v.u = p & 0xFFFF0000u;
  return v.f;
}
__device__ __forceinline__ uint32_t pk2bf(float a, float b) {  // packed RNE pair
  return (uint32_t)f2bf(a) | ((uint32_t)f2bf(b) << 16);
}

// DPP add within each 16-lane row (one head). bound_ctrl=1, full masks.
template <int CTRL>
__device__ __forceinline__ float dpp_add(float x) {
  int y = __builtin_amdgcn_update_dpp(0, __builtin_bit_cast(int, x),
                                      CTRL, 0xF, 0xF, true);
  return x + __builtin_bit_cast(float, y);
}
__device__ __forceinline__ float row16_sum(float x) {
  x = dpp_add<0xB1>(x);    // quad_perm xor1
  x = dpp_add<0x4E>(x);    // quad_perm xor2
  x = dpp_add<0x141>(x);   // row_half_mirror
  x = dpp_add<0x140>(x);   // row_mirror
  return x;
}

// ---------------------------------------------------------------------------
// Kernel 1: repack projection weights -> bf16 Wc[NPAD][128]; Wout -> bf16.
// ---------------------------------------------------------------------------
__global__ __launch_bounds__(256) void prep_kernel(
    const float* __restrict__ Wq, const float* __restrict__ Wk,
    const float* __restrict__ Wv, const float* __restrict__ Wb,
    const float* __restrict__ Wg, const float* __restrict__ Wout,
    u16* __restrict__ Wc, u16* __restrict__ Woutb)
{
  int t = blockIdx.x * 256 + threadIdx.x;
  if (t < NPAD * INF) {
    int n = t >> 7, k = t & 127;
    float v = 0.0f;
    if (n < 128)       v = Wq[n * 128 + k];
    else if (n < 256)  v = Wg[(n - 128) * 128 + k];
    else if (n < 512) {
      int m = n - 256, h = m >> 6, c = m & 63;
      v = (c < 32) ? Wk[(h * 32 + c) * 128 + k] : Wv[(h * 32 + (c - 32)) * 128 + k];
    } else if (n < 516) v = Wb[(n - 512) * 128 + k];
    Wc[t] = f2bf(v);
  } else if (t < NPAD * INF + OUTF * 128) {
    int u = t - NPAD * INF;
    Woutb[u] = f2bf(Wout[u]);
  }
}

// ---------------------------------------------------------------------------
// Kernel 2: projection GEMM, operand-swapped: D = Wc_tile(16n x 128k) x
// Z_edges(128k x 16e). D: col(lane&15)=edge, rows(blk*4+r)=4 CONSECUTIVE
// n-features -> packed 8B bf16x4 stores (one per sub-tile) instead of 8
// scalar 2B stores. Region branch is uniform per nt (boundaries are x16).
// ---------------------------------------------------------------------------
__global__ __launch_bounds__(256) void proj_kernel(
    const float* __restrict__ Z, const u16* __restrict__ Wc,
    const float* __restrict__ bg,
    u16* __restrict__ qb, u16* __restrict__ gb,
    u16* __restrict__ kvb, float* __restrict__ bb)
{
  const int wid = threadIdx.x >> 6, lane = threadIdx.x & 63;
  const int ml = lane & 15, blk = lane >> 4;
  const long e0 = (long)blockIdx.x * 128 + wid * 32;

  // Z fragments (B-operand): edge = e0 + s*16 + ml, k = kk*32 + blk*8 + j
  bf16x8 zfr[2][4];
#pragma unroll
  for (int s = 0; s < 2; ++s) {
    long er = e0 + s * 16 + ml; if (er > EDGES - 1) er = EDGES - 1;
    const float* zp = Z + er * INF + blk * 8;
#pragma unroll
    for (int kk = 0; kk < 4; ++kk) {
      float4 f0 = *(const float4*)(zp + kk * 32);
      float4 f1 = *(const float4*)(zp + kk * 32 + 4);
      uint32_t p0 = pk2bf(f0.x, f0.y), p1 = pk2bf(f0.z, f0.w);
      uint32_t p2 = pk2bf(f1.x, f1.y), p3 = pk2bf(f1.z, f1.w);
      zfr[s][kk] = __builtin_bit_cast(bf16x8, (uint4){p0, p1, p2, p3});
    }
  }

  for (int nt = 0; nt < NTILES; ++nt) {
    // Wc fragments (A-operand): row n = nt*16 + ml
    bf16x8 wfr[4];
#pragma unroll
    for (int kk = 0; kk < 4; ++kk)
      wfr[kk] = *(const bf16x8*)(Wc + (nt * 16 + ml) * INF + kk * 32 + blk * 8);

    f32x4 acc[2];
    acc[0] = (f32x4){0.f, 0.f, 0.f, 0.f};
    acc[1] = (f32x4){0.f, 0.f, 0.f, 0.f};
#pragma unroll
    for (int kk = 0; kk < 4; ++kk) {
      acc[0] = __builtin_amdgcn_mfma_f32_16x16x32_bf16(wfr[kk], zfr[0][kk], acc[0], 0, 0, 0);
      acc[1] = __builtin_amdgcn_mfma_f32_16x16x32_bf16(wfr[kk], zfr[1][kk], acc[1], 0, 0, 0);
    }

    const int n0 = nt * 16 + blk * 4;   // 4 consecutive n: n0..n0+3
    if (nt < 8) {                       // ---- q region
#pragma unroll
      for (int s = 0; s < 2; ++s) {
        long e = e0 + s * 16 + ml; if (e >= EDGES) continue;
        uint2 pk = {pk2bf(acc[s][0], acc[s][1]), pk2bf(acc[s][2], acc[s][3])};
        *(uint2*)(qb + e * 128 + n0) = pk;
      }
    } else if (nt < 16) {               // ---- g region (sigmoid + bg)
      const float4 b4 = *(const float4*)(bg + (n0 - 128));
#pragma unroll
      for (int s = 0; s < 2; ++s) {
        long e = e0 + s * 16 + ml; if (e >= EDGES) continue;
        float s0 = 1.0f / (1.0f + __expf(-(acc[s][0] + b4.x)));
        float s1 = 1.0f / (1.0f + __expf(-(acc[s][1] + b4.y)));
        float s2 = 1.0f / (1.0f + __expf(-(acc[s][2] + b4.z)));
        float s3 = 1.0f / (1.0f + __expf(-(acc[s][3] + b4.w)));
        uint2 pk = {pk2bf(s0, s1), pk2bf(s2, s3)};
        *(uint2*)(gb + e * 128 + (n0 - 128)) = pk;
      }
    } else if (nt < 32) {               // ---- kv region
#pragma unroll
      for (int s = 0; s < 2; ++s) {
        long e = e0 + s * 16 + ml; if (e >= EDGES) continue;
        uint2 pk = {pk2bf(acc[s][0], acc[s][1]), pk2bf(acc[s][2], acc[s][3])};
        *(uint2*)(kvb + e * 256 + (n0 - 256)) = pk;
      }
    } else if (blk == 0) {              // ---- b region (rows 512..515 = 4 heads)
#pragma unroll
      for (int s = 0; s < 2; ++s) {
        long e = e0 + s * 16 + ml; if (e >= EDGES) continue;
        *(f32x4*)(bb + e * 4) = acc[s];
      }
    }
  }
}

// ---------------------------------------------------------------------------
// Kernel 3: gathered attention. One wave per NEDGE edges (serial, unroll-2
// for cross-edge ILP). Lane = (h=lane>>4, dims 2*(lane&15)..+1).
// ---------------------------------------------------------------------------
__global__ __launch_bounds__(256) void attn_kernel(
    const int* __restrict__ klist, const u16* qb,
    const u16* __restrict__ gb, const u16* __restrict__ kvb,
    const float* __restrict__ bb, u16* xb)
{
  const int wid = threadIdx.x >> 6;
  const int lane = threadIdx.x & 63;
  const int ebase = __builtin_amdgcn_readfirstlane((blockIdx.x * 4 + wid) * NEDGE);

  const int h = lane >> 4;
  const int kvo = h * 64 + (lane & 15) * 2;
  const float scale = 0.17677669529663687f;  // 1/sqrt(32)

#pragma unroll 2
  for (int t = 0; t < NEDGE; ++t) {
    const int e = ebase + t;   // grid sized exactly: no bounds check needed
    const uint32_t q2 = *(const uint32_t*)(qb + (size_t)e * 128 + 2 * lane);
    const uint32_t g2 = *(const uint32_t*)(gb + (size_t)e * 128 + 2 * lane);
    const float q0 = bflo(q2), q1 = bfhi(q2);

    float sc[MAXK];
    uint32_t vvm[MAXK];
    const int* kl = klist + (size_t)e * 32;
#pragma unroll
    for (int nb = 0; nb < MAXK; ++nb) {
      const int ii = kl[nb];
      const int jj = kl[16 + nb];
      const bool valid = (ii >= 0);
      const int is = valid ? ii : 0;
      const int js = valid ? jj : 0;
      const u16* kvrow = kvb + (size_t)is * 256;
      uint32_t kki = *(const uint32_t*)(kvrow + kvo);        // k pair
      uint32_t vvi = *(const uint32_t*)(kvrow + kvo + 32);   // v pair
      float p = q0 * bflo(kki) + q1 * bfhi(kki);
      p = row16_sum(p);                                      // head-wide dot
      float bj = bb[(size_t)js * 4 + h];
      sc[nb]  = valid ? (scale * p + bj) : 0.0f;
      vvm[nb] = valid ? vvi : 0u;
    }

    float m = sc[0];
#pragma unroll
    for (int nb = 1; nb < MAXK; ++nb) m = fmaxf(m, sc[nb]);
    float s = 0.f, a0 = 0.f, a1 = 0.f;
#pragma unroll
    for (int nb = 0; nb < MAXK; ++nb) {
      float al = __expf(sc[nb] - m);
      s += al;
      a0 += al * bflo(vvm[nb]);
      a1 += al * bfhi(vvm[nb]);
    }
    float inv = 1.0f / s;
    uint32_t xo = pk2bf(bflo(g2) * a0 * inv, bfhi(g2) * a1 * inv);
    *(uint32_t*)(xb + (size_t)e * 128 + 2 * lane) = xo;
  }
}

// ---------------------------------------------------------------------------
// Kernel 4: out = x @ Wout^T + bout, operand-swapped like proj: D rows = 4
// consecutive out-features -> one dwordx4 f32 store per sub-tile.
// ---------------------------------------------------------------------------
__global__ __launch_bounds__(256) void outgemm_kernel(
    const u16* xb, const u16* __restrict__ Woutb,
    const float* __restrict__ bout, float* __restrict__ out)
{
  const int wid = threadIdx.x >> 6, lane = threadIdx.x & 63;
  const int ml = lane & 15, blk = lane >> 4;
  const long e0 = (long)blockIdx.x * 128 + wid * 32;

  bf16x8 xfr[2][4];
#pragma unroll
  for (int s = 0; s < 2; ++s) {
    long er = e0 + s * 16 + ml; if (er > EDGES - 1) er = EDGES - 1;
#pragma unroll
    for (int kk = 0; kk < 4; ++kk)
      xfr[s][kk] = *(const bf16x8*)(xb + er * 128 + kk * 32 + blk * 8);
  }

#pragma unroll
  for (int nt = 0; nt < 8; ++nt) {
    bf16x8 wfr[4];
#pragma unroll
    for (int kk = 0; kk < 4; ++kk)
      wfr[kk] = *(const bf16x8*)(Woutb + (nt * 16 + ml) * 128 + kk * 32 + blk * 8);

    f32x4 acc[2];
    acc[0] = (f32x4){0.f, 0.f, 0.f, 0.f};
    acc[1] = (f32x4){0.f, 0.f, 0.f, 0.f};
#pragma unroll
    for (int kk = 0; kk < 4; ++kk) {
      acc[0] = __builtin_amdgcn_mfma_f32_16x16x32_bf16(wfr[kk], xfr[0][kk], acc[0], 0, 0, 0);
      acc[1] = __builtin_amdgcn_mfma_f32_16x16x32_bf16(wfr[kk], xfr[1][kk], acc[1], 0, 0, 0);
    }

    const int o0 = nt * 16 + blk * 4;
    const float4 b4 = *(const float4*)(bout + o0);
#pragma unroll
    for (int s = 0; s < 2; ++s) {
      long e = e0 + s * 16 + ml; if (e >= EDGES) continue;
      float4 r = {acc[s][0] + b4.x, acc[s][1] + b4.y,
                  acc[s][2] + b4.z, acc[s][3] + b4.w};
      *(float4*)(out + e * 128 + o0) = r;
    }
  }
}

// ---------------------------------------------------------------------------
extern "C" void kernel_launch(void* const* d_in, const int* in_sizes, int n_in,
                              void* d_out, int out_size, void* d_ws, size_t ws_size,
                              hipStream_t stream) {
  const float* Z     = (const float*)d_in[0];
  const int*   klist = (const int*)  d_in[1];
  const float* Wq    = (const float*)d_in[2];
  const float* Wk    = (const float*)d_in[3];
  const float* Wv    = (const float*)d_in[4];
  const float* Wb    = (const float*)d_in[5];
  const float* Wg    = (const float*)d_in[6];
  const float* bg    = (const float*)d_in[7];
  const float* Wout  = (const float*)d_in[8];
  const float* bout  = (const float*)d_in[9];
  float* out = (float*)d_out;

  char* ws = (char*)d_ws;
  u16*   Wc    = (u16*)(ws);                        //   528*128*2   = 135168
  u16*   Woutb = (u16*)(ws + 135168);               //   128*128*2   =  32768
  u16*   qb    = (u16*)(ws + 167936);               // E*128*2 = 51.2 MB (also xb)
  u16*   gb    = (u16*)(ws + 51367936);             // E*128*2 = 51.2 MB
  u16*   kvb   = (u16*)(ws + 102567936);            // E*256*2 = 102.4 MB
  float* bb    = (float*)(ws + 204967936);          // E*4*4   = 3.2 MB
  u16*   xb    = qb;                                // alias: per-edge RAW-safe

  prep_kernel<<<(NPAD * INF + OUTF * 128 + 255) / 256, 256, 0, stream>>>(
      Wq, Wk, Wv, Wb, Wg, Wout, Wc, Woutb);
  proj_kernel<<<(EDGES + 127) / 128, 256, 0, stream>>>(
      Z, Wc, bg, qb, gb, kvb, bb);
  attn_kernel<<<EDGES / (4 * NEDGE), 256, 0, stream>>>(   // 6250 blocks exact
      klist, qb, gb, kvb, bb, xb);
  outgemm_kernel<<<(EDGES + 127) / 128, 256, 0, stream>>>(
      xb, Woutb, bout, out);
}